// Round 1
// baseline (2648.154 us; speedup 1.0000x reference)
//
#include <hip/hip_runtime.h>

#define FDIM 256
#define FV4 64   // float4 per feature row

// ---------------- CSR build ----------------
__global__ void k_hist(const int* __restrict__ dst, int* __restrict__ deg, int E) {
  int e = blockIdx.x * 256 + threadIdx.x;
  if (e < E) atomicAdd(&deg[dst[e]], 1);
}

__global__ __launch_bounds__(1024) void k_scan(const int* __restrict__ deg,
    int* __restrict__ rowptr, int* __restrict__ cursor, int n) {
  __shared__ int sm[1024];
  __shared__ int carry;
  int tid = threadIdx.x;
  if (tid == 0) carry = 0;
  __syncthreads();
  for (int base = 0; base < n; base += 1024) {
    int v = (base + tid < n) ? deg[base + tid] : 0;
    sm[tid] = v;
    __syncthreads();
    for (int off = 1; off < 1024; off <<= 1) {
      int t = (tid >= off) ? sm[tid - off] : 0;
      __syncthreads();
      sm[tid] += t;
      __syncthreads();
    }
    if (base + tid < n) {
      int excl = carry + sm[tid] - v;
      rowptr[base + tid] = excl;
      cursor[base + tid] = excl;   // in-place over deg is safe: read-before-write per chunk
    }
    __syncthreads();
    if (tid == 0) carry += sm[1023];
    __syncthreads();
  }
  if (tid == 0) rowptr[n] = carry;
}

__global__ void k_scatter(const int* __restrict__ src, const int* __restrict__ dst,
    int* __restrict__ cursor, int* __restrict__ esrc, int E) {
  int e = blockIdx.x * 256 + threadIdx.x;
  if (e < E) {
    int p = atomicAdd(&cursor[dst[e]], 1);
    esrc[p] = src[e];
  }
}

// ---------------- aggregation: out[d] = sum_{e: dst=d} h[src[e]] ----------------
// One wave (64 lanes) per node, float4 per lane covers all 256 floats.
__global__ __launch_bounds__(256) void k_agg(const float* __restrict__ h,
    const int* __restrict__ rowptr, const int* __restrict__ esrc,
    float* __restrict__ out, int n) {
  int wid = ((blockIdx.x * 256) + threadIdx.x) >> 6;
  int lane = threadIdx.x & 63;
  if (wid >= n) return;
  int beg = rowptr[wid], end = rowptr[wid + 1];
  const float4* hv = (const float4*)h;
  float ax0 = 0, ay0 = 0, az0 = 0, aw0 = 0;
  float ax1 = 0, ay1 = 0, az1 = 0, aw1 = 0;
  int e = beg;
  for (; e + 2 <= end; e += 2) {
    int s0 = esrc[e], s1 = esrc[e + 1];
    float4 v0 = hv[(size_t)s0 * FV4 + lane];
    float4 v1 = hv[(size_t)s1 * FV4 + lane];
    ax0 += v0.x; ay0 += v0.y; az0 += v0.z; aw0 += v0.w;
    ax1 += v1.x; ay1 += v1.y; az1 += v1.z; aw1 += v1.w;
  }
  if (e < end) {
    float4 v = hv[(size_t)esrc[e] * FV4 + lane];
    ax0 += v.x; ay0 += v.y; az0 += v.z; aw0 += v.w;
  }
  float4 r;
  r.x = ax0 + ax1; r.y = ay0 + ay1; r.z = az0 + az1; r.w = aw0 + aw1;
  ((float4*)out)[(size_t)wid * FV4 + lane] = r;
}

// ---------------- C[M,256] = A[M,256] @ W[256,256]^T + bias ----------------
// Block tile 128x128, 256 threads, 8x8 per thread, K chunks of 16.
__global__ __launch_bounds__(256) void k_mm_bias(const float* __restrict__ A,
    const float* __restrict__ W, const float* __restrict__ bias,
    float* __restrict__ C, int M) {
  __shared__ float As[16][128];   // [k][row]
  __shared__ float Bs[16][128];   // [k][col] = W[col][k]
  int tid = threadIdx.x;
  int r0 = blockIdx.x * 128, o0 = blockIdx.y * 128;
  int ti = tid >> 4, tj = tid & 15;
  int lr = tid >> 1;              // 0..127
  int lk = (tid & 1) * 8;         // 0 or 8
  float acc[8][8] = {};
  for (int k0 = 0; k0 < 256; k0 += 16) {
    int r = r0 + lr;
    float4 v0 = make_float4(0.f, 0.f, 0.f, 0.f);
    float4 v1 = make_float4(0.f, 0.f, 0.f, 0.f);
    if (r < M) {
      v0 = *(const float4*)(A + (size_t)r * 256 + k0 + lk);
      v1 = *(const float4*)(A + (size_t)r * 256 + k0 + lk + 4);
    }
    As[lk + 0][lr] = v0.x; As[lk + 1][lr] = v0.y; As[lk + 2][lr] = v0.z; As[lk + 3][lr] = v0.w;
    As[lk + 4][lr] = v1.x; As[lk + 5][lr] = v1.y; As[lk + 6][lr] = v1.z; As[lk + 7][lr] = v1.w;
    float4 w0 = *(const float4*)(W + (size_t)(o0 + lr) * 256 + k0 + lk);
    float4 w1 = *(const float4*)(W + (size_t)(o0 + lr) * 256 + k0 + lk + 4);
    Bs[lk + 0][lr] = w0.x; Bs[lk + 1][lr] = w0.y; Bs[lk + 2][lr] = w0.z; Bs[lk + 3][lr] = w0.w;
    Bs[lk + 4][lr] = w1.x; Bs[lk + 5][lr] = w1.y; Bs[lk + 6][lr] = w1.z; Bs[lk + 7][lr] = w1.w;
    __syncthreads();
#pragma unroll
    for (int k = 0; k < 16; ++k) {
      float a[8], b[8];
      *(float4*)&a[0] = *(const float4*)&As[k][ti * 8];
      *(float4*)&a[4] = *(const float4*)&As[k][ti * 8 + 4];
      *(float4*)&b[0] = *(const float4*)&Bs[k][tj * 8];
      *(float4*)&b[4] = *(const float4*)&Bs[k][tj * 8 + 4];
#pragma unroll
      for (int i = 0; i < 8; ++i)
#pragma unroll
        for (int j = 0; j < 8; ++j)
          acc[i][j] += a[i] * b[j];
    }
    __syncthreads();
  }
#pragma unroll
  for (int i = 0; i < 8; ++i) {
    int r = r0 + ti * 8 + i;
    if (r < M) {
#pragma unroll
      for (int j = 0; j < 8; j += 4) {
        int o = o0 + tj * 8 + j;
        float4 v;
        v.x = acc[i][j + 0] + bias[o + 0];
        v.y = acc[i][j + 1] + bias[o + 1];
        v.z = acc[i][j + 2] + bias[o + 2];
        v.w = acc[i][j + 3] + bias[o + 3];
        *(float4*)(C + (size_t)r * 256 + o) = v;
      }
    }
  }
}

// ---------------- batchnorm ----------------
__global__ __launch_bounds__(256) void k_bn_stats(const float* __restrict__ h,
    float* __restrict__ sum, float* __restrict__ sumsq, int n) {
  int f = threadIdx.x;
  float s = 0.f, q = 0.f;
  for (int r = blockIdx.x; r < n; r += gridDim.x) {
    float v = h[(size_t)r * 256 + f];
    s += v; q += v * v;
  }
  atomicAdd(&sum[f], s);
  atomicAdd(&sumsq[f], q);
}

__global__ __launch_bounds__(256) void k_bn_apply(float* __restrict__ h,
    const float* __restrict__ sum, const float* __restrict__ sumsq,
    const float* __restrict__ gamma, const float* __restrict__ beta, int n) {
  int f = threadIdx.x;
  float inv = 1.0f / (float)n;
  float mean = sum[f] * inv;
  float var = sumsq[f] * inv - mean * mean;
  float sc = gamma[f] * rsqrtf(var + 1e-5f);
  float sh = beta[f] - mean * sc;
  for (int r = blockIdx.x; r < n; r += gridDim.x) {
    size_t idx = (size_t)r * 256 + f;
    h[idx] = h[idx] * sc + sh;
  }
}

// ---------------- out[i][j] = sum_k H1[k][i] * H2[k][j], split-K + atomics ----------------
__global__ __launch_bounds__(256) void k_final(const float* __restrict__ H1,
    const float* __restrict__ H2, float* __restrict__ out, int n) {
  __shared__ float As[16][64];
  __shared__ float Bs[16][64];
  int tid = threadIdx.x;
  int ti = tid >> 4, tj = tid & 15;
  int i0 = blockIdx.x * 64, j0 = blockIdx.y * 64;
  int kc = (n + gridDim.z - 1) / gridDim.z;
  int kb = blockIdx.z * kc;
  int ke = min(n, kb + kc);
  int lk = tid >> 4;
  int lc = (tid & 15) * 4;
  float acc[4][4] = {};
  for (int kk = kb; kk < ke; kk += 16) {
    int k = kk + lk;
    float4 a = make_float4(0.f, 0.f, 0.f, 0.f);
    float4 b = make_float4(0.f, 0.f, 0.f, 0.f);
    if (k < ke) {
      a = *(const float4*)(H1 + (size_t)k * 256 + i0 + lc);
      b = *(const float4*)(H2 + (size_t)k * 256 + j0 + lc);
    }
    *(float4*)&As[lk][lc] = a;
    *(float4*)&Bs[lk][lc] = b;
    __syncthreads();
#pragma unroll
    for (int k2 = 0; k2 < 16; ++k2) {
      float av[4], bv[4];
      *(float4*)&av[0] = *(const float4*)&As[k2][ti * 4];
      *(float4*)&bv[0] = *(const float4*)&Bs[k2][tj * 4];
#pragma unroll
      for (int i = 0; i < 4; ++i)
#pragma unroll
        for (int j = 0; j < 4; ++j)
          acc[i][j] += av[i] * bv[j];
    }
    __syncthreads();
  }
#pragma unroll
  for (int i = 0; i < 4; ++i)
#pragma unroll
    for (int j = 0; j < 4; ++j)
      atomicAdd(&out[(size_t)(i0 + ti * 4 + i) * 256 + (j0 + tj * 4 + j)], acc[i][j]);
}

extern "C" void kernel_launch(void* const* d_in, const int* in_sizes, int n_in,
                              void* d_out, int out_size, void* d_ws, size_t ws_size,
                              hipStream_t stream) {
  const float* feature = (const float*)d_in[0];
  const int* src1 = (const int*)d_in[1];
  const int* dst1 = (const int*)d_in[2];
  const int* src2 = (const int*)d_in[3];
  const int* dst2 = (const int*)d_in[4];
  const float* W1 = (const float*)d_in[5];
  const float* b1 = (const float*)d_in[6];
  const float* W2 = (const float*)d_in[7];
  const float* b2 = (const float*)d_in[8];
  const float* W3 = (const float*)d_in[9];
  const float* b3 = (const float*)d_in[10];
  const float* gamma = (const float*)d_in[11];
  const float* beta = (const float*)d_in[12];
  const int N = in_sizes[0] / FDIM;
  const int E = in_sizes[1];
  float* out = (float*)d_out;

  char* ws = (char*)d_ws;
  size_t nf_bytes = (size_t)N * FDIM * sizeof(float);
  float* X  = (float*)(ws);
  float* Y  = (float*)(ws + nf_bytes);
  float* O1 = (float*)(ws + 2 * nf_bytes);
  char* p = ws + 3 * nf_bytes;
  int* rowptr = (int*)p; p += (size_t)(N + 1) * sizeof(int);
  int* cursor = (int*)p; p += (size_t)N * sizeof(int);
  int* esrc   = (int*)p; p += (size_t)E * sizeof(int);
  float* bnsum = (float*)p; p += FDIM * sizeof(float);
  float* bnsq  = (float*)p;

  const int eb = (E + 255) / 256;
  const int aggb = (N + 3) / 4;          // 4 waves/block, 1 wave per node
  dim3 mmg((N + 127) / 128, 2);

  auto build = [&](const int* s, const int* d) {
    hipMemsetAsync(cursor, 0, (size_t)N * sizeof(int), stream);
    k_hist<<<eb, 256, 0, stream>>>(d, cursor, E);
    k_scan<<<1, 1024, 0, stream>>>(cursor, rowptr, cursor, N);
    k_scatter<<<eb, 256, 0, stream>>>(s, d, cursor, esrc, E);
  };
  auto agg = [&](const float* in, float* o) {
    k_agg<<<aggb, 256, 0, stream>>>(in, rowptr, esrc, o, N);
  };
  auto mm = [&](const float* A, const float* W, const float* b, float* C) {
    k_mm_bias<<<mmg, 256, 0, stream>>>(A, W, b, C, N);
  };
  auto branch = [&](float* o) {
    agg(feature, X); agg(X, Y);
    mm(Y, W1, b1, X);
    hipMemsetAsync(bnsum, 0, 2 * FDIM * sizeof(float), stream);
    k_bn_stats<<<512, 256, 0, stream>>>(X, bnsum, bnsq, N);
    k_bn_apply<<<512, 256, 0, stream>>>(X, bnsum, bnsq, gamma, beta, N);
    agg(X, Y); agg(Y, X);
    mm(X, W2, b2, Y);
    agg(Y, X); agg(X, Y);
    mm(Y, W3, b3, o);
  };

  build(src1, dst1);
  branch(O1);
  build(src2, dst2);
  branch(X);   // branch-2 output lands in X (dead at that point inside the branch)

  hipMemsetAsync(out, 0, (size_t)FDIM * FDIM * sizeof(float), stream);
  k_final<<<dim3(4, 4, 48), 256, 0, stream>>>(O1, X, out, N);
}

// Round 2
// 2564.424 us; speedup vs baseline: 1.0327x; 1.0327x over previous
//
#include <hip/hip_runtime.h>

#define FDIM 256
#define FV4 64
#define GRAM_KS 128

// ---------------- CSR build ----------------
__global__ void k_hist(const int* __restrict__ dst, int* __restrict__ deg, int E) {
  int e = blockIdx.x * 256 + threadIdx.x;
  if (e < E) atomicAdd(&deg[dst[e]], 1);
}

__global__ __launch_bounds__(1024) void k_scan(const int* __restrict__ deg,
    int* __restrict__ rowptr, int* __restrict__ cursor, int n) {
  __shared__ int sm[1024];
  __shared__ int carry;
  int tid = threadIdx.x;
  if (tid == 0) carry = 0;
  __syncthreads();
  for (int base = 0; base < n; base += 1024) {
    int v = (base + tid < n) ? deg[base + tid] : 0;
    sm[tid] = v;
    __syncthreads();
    for (int off = 1; off < 1024; off <<= 1) {
      int t = (tid >= off) ? sm[tid - off] : 0;
      __syncthreads();
      sm[tid] += t;
      __syncthreads();
    }
    if (base + tid < n) {
      int excl = carry + sm[tid] - v;
      rowptr[base + tid] = excl;
      cursor[base + tid] = excl;
    }
    __syncthreads();
    if (tid == 0) carry += sm[1023];
    __syncthreads();
  }
  if (tid == 0) rowptr[n] = carry;
}

__global__ void k_scatter(const int* __restrict__ src, const int* __restrict__ dst,
    int* __restrict__ cursor, int* __restrict__ esrc, int E) {
  int e = blockIdx.x * 256 + threadIdx.x;
  if (e < E) {
    int p = atomicAdd(&cursor[dst[e]], 1);
    esrc[p] = src[e];
  }
}

// ---------------- feature aggregation (one wave per node) ----------------
__global__ __launch_bounds__(256) void k_agg(const float* __restrict__ h,
    const int* __restrict__ rowptr, const int* __restrict__ esrc,
    float* __restrict__ out, int n) {
  int wid = ((blockIdx.x * 256) + threadIdx.x) >> 6;
  int lane = threadIdx.x & 63;
  if (wid >= n) return;
  int beg = rowptr[wid], end = rowptr[wid + 1];
  const float4* hv = (const float4*)h;
  float ax0 = 0, ay0 = 0, az0 = 0, aw0 = 0;
  float ax1 = 0, ay1 = 0, az1 = 0, aw1 = 0;
  int e = beg;
  for (; e + 2 <= end; e += 2) {
    int s0 = esrc[e], s1 = esrc[e + 1];
    float4 v0 = hv[(size_t)s0 * FV4 + lane];
    float4 v1 = hv[(size_t)s1 * FV4 + lane];
    ax0 += v0.x; ay0 += v0.y; az0 += v0.z; aw0 += v0.w;
    ax1 += v1.x; ay1 += v1.y; az1 += v1.z; aw1 += v1.w;
  }
  if (e < end) {
    float4 v = hv[(size_t)esrc[e] * FV4 + lane];
    ax0 += v.x; ay0 += v.y; az0 += v.z; aw0 += v.w;
  }
  float4 r;
  r.x = ax0 + ax1; r.y = ay0 + ay1; r.z = az0 + az1; r.w = aw0 + aw1;
  ((float4*)out)[(size_t)wid * FV4 + lane] = r;
}

// ---------------- scalar (vector) aggregation ----------------
__global__ void k_deg(const int* __restrict__ rowptr, float* __restrict__ out, int n) {
  int v = blockIdx.x * 256 + threadIdx.x;
  if (v < n) out[v] = (float)(rowptr[v + 1] - rowptr[v]);
}

__global__ void k_aggv(const float* __restrict__ in, const int* __restrict__ rowptr,
    const int* __restrict__ esrc, float* __restrict__ out, int n) {
  int v = blockIdx.x * 256 + threadIdx.x;
  if (v >= n) return;
  int beg = rowptr[v], end = rowptr[v + 1];
  float s = 0.f;
  for (int e = beg; e < end; ++e) s += in[esrc[e]];
  out[v] = s;
}

// ---------------- Gram: partial[z] = X_chunk^T Y_chunk (128x128 tile/block) ----------------
__global__ __launch_bounds__(256) void k_gram(const float* __restrict__ Xm,
    const float* __restrict__ Ym, float* __restrict__ partial, int n) {
  __shared__ float Xs[16][128];
  __shared__ float Ys[16][128];
  int tid = threadIdx.x;
  int i0 = blockIdx.x * 128, j0 = blockIdx.y * 128;
  int z = blockIdx.z;
  int chunk = (n + GRAM_KS - 1) / GRAM_KS;
  int rb = z * chunk, re = min(n, rb + chunk);
  int lk = tid >> 4;           // 0..15
  int lc = (tid & 15) * 8;     // 0..120
  int ti = tid >> 4, tj = tid & 15;
  float acc[8][8] = {};
  for (int rr = rb; rr < re; rr += 16) {
    int r = rr + lk;
    float4 a0 = {0,0,0,0}, a1 = {0,0,0,0}, b0 = {0,0,0,0}, b1 = {0,0,0,0};
    if (r < re) {
      const float* xp = Xm + (size_t)r * 256 + i0 + lc;
      const float* yp = Ym + (size_t)r * 256 + j0 + lc;
      a0 = *(const float4*)xp; a1 = *(const float4*)(xp + 4);
      b0 = *(const float4*)yp; b1 = *(const float4*)(yp + 4);
    }
    *(float4*)&Xs[lk][lc] = a0; *(float4*)&Xs[lk][lc + 4] = a1;
    *(float4*)&Ys[lk][lc] = b0; *(float4*)&Ys[lk][lc + 4] = b1;
    __syncthreads();
#pragma unroll
    for (int k = 0; k < 16; ++k) {
      float av[8], bv[8];
      *(float4*)&av[0] = *(const float4*)&Xs[k][ti * 8];
      *(float4*)&av[4] = *(const float4*)&Xs[k][ti * 8 + 4];
      *(float4*)&bv[0] = *(const float4*)&Ys[k][tj * 8];
      *(float4*)&bv[4] = *(const float4*)&Ys[k][tj * 8 + 4];
#pragma unroll
      for (int i = 0; i < 8; ++i)
#pragma unroll
        for (int j = 0; j < 8; ++j) acc[i][j] += av[i] * bv[j];
    }
    __syncthreads();
  }
  float* pout = partial + (size_t)z * 65536;
#pragma unroll
  for (int i = 0; i < 8; ++i) {
    int row = i0 + ti * 8 + i;
#pragma unroll
    for (int j = 0; j < 8; j += 4)
      *(float4*)(pout + (size_t)row * 256 + j0 + tj * 8 + j) = *(float4*)&acc[i][j];
  }
}

__global__ void k_gram_reduce(const float* __restrict__ partial, float* __restrict__ C) {
  int idx = blockIdx.x * 256 + threadIdx.x;
  float s = 0.f;
  for (int z = 0; z < GRAM_KS; ++z) s += partial[(size_t)z * 65536 + idx];
  C[idx] = s;
}

// ---------------- weighted column sums: outA=G^T wA, outB=G^T wB, outS=colsum G ----------------
__global__ __launch_bounds__(256) void k_matvec3(const float* __restrict__ G,
    const float* __restrict__ wA, const float* __restrict__ wB,
    float* outA, float* outB, float* outS, int n) {
  int f = threadIdx.x;
  float sA = 0.f, sB = 0.f, sS = 0.f;
  for (int r = blockIdx.x; r < n; r += gridDim.x) {
    float v = G[(size_t)r * 256 + f];
    if (wA) sA += v * wA[r];
    if (wB) sB += v * wB[r];
    sS += v;
  }
  if (outA) atomicAdd(&outA[f], sA);
  if (outB) atomicAdd(&outB[f], sB);
  atomicAdd(&outS[f], sS);
}

// ---------------- 8 scalar reductions over d/e vectors ----------------
__global__ __launch_bounds__(256) void k_dots(const float* __restrict__ d1,
    const float* __restrict__ e1, const float* __restrict__ d2,
    const float* __restrict__ e2, float* scal, int n) {
  int i = blockIdx.x * 256 + threadIdx.x;
  float a = 0, b = 0, c = 0, d = 0;
  if (i < n) { a = d1[i]; b = e1[i]; c = d2[i]; d = e2[i]; }
  float v[8] = { b * d, b * c, b, a * d, a * c, a, d, c };
#pragma unroll
  for (int j = 0; j < 8; ++j) {
    float x = v[j];
    for (int off = 32; off; off >>= 1) x += __shfl_down(x, off);
    v[j] = x;
  }
  if ((threadIdx.x & 63) == 0)
#pragma unroll
    for (int j = 0; j < 8; ++j) atomicAdd(&scal[j], v[j]);
}

// ---------------- t_j = w_j^T C w_j ; mv_j = w_j . m_raw ----------------
__global__ __launch_bounds__(256) void k_quad(const float* __restrict__ C,
    const float* __restrict__ W1, const float* __restrict__ m_raw,
    float* __restrict__ t, float* __restrict__ mv) {
  __shared__ float w[256];
  __shared__ float r1[256], r2[256];
  int j = blockIdx.x, tid = threadIdx.x;
  w[tid] = W1[j * 256 + tid];
  __syncthreads();
  float v = 0.f;
  for (int k = 0; k < 256; ++k) v += w[k] * C[k * 256 + tid];
  r1[tid] = v * w[tid];
  r2[tid] = w[tid] * m_raw[tid];
  __syncthreads();
  for (int off = 128; off; off >>= 1) {
    if (tid < off) { r1[tid] += r1[tid + off]; r2[tid] += r2[tid + off]; }
    __syncthreads();
  }
  if (tid == 0) { t[j] = r1[0]; mv[j] = r2[0]; }
}

// ---------------- BN coefficients + x = W3 W2 c, y = W3 b2 ----------------
__global__ __launch_bounds__(256) void k_bncoef(const float* __restrict__ t,
    const float* __restrict__ mv, const float* __restrict__ b1,
    const float* __restrict__ gamma, const float* __restrict__ beta,
    const float* __restrict__ W2, const float* __restrict__ W3,
    const float* __restrict__ b2, float* Dv, float* xv, float* yv, int n) {
  __shared__ float c[256], u[256];
  int j = threadIdx.x;
  float invn = 1.f / (float)n;
  float mean = mv[j] * invn + b1[j];
  float E2 = t[j] * invn + 2.f * b1[j] * mv[j] * invn + b1[j] * b1[j];
  float var = E2 - mean * mean;
  float D = gamma[j] * rsqrtf(var + 1e-5f);
  Dv[j] = D;
  c[j] = D * (b1[j] - mean) + beta[j];
  __syncthreads();
  float uu = 0.f;
  for (int k = 0; k < 256; ++k) uu += W2[j * 256 + k] * c[k];
  u[j] = uu;
  __syncthreads();
  float xx = 0.f, yy = 0.f;
  for (int k = 0; k < 256; ++k) {
    xx += W3[j * 256 + k] * u[k];
    yy += W3[j * 256 + k] * b2[k];
  }
  xv[j] = xx;
  yv[j] = yy;
}

// ---------------- small 256x256 matmul: C = A'(s) B', optional transposes/accum ----------------
__global__ __launch_bounds__(256) void k_mm_small(float* __restrict__ Cm,
    const float* __restrict__ A, const float* __restrict__ B,
    const float* __restrict__ s, int transA, int transB, int accum) {
  __shared__ float a[256];
  int i = blockIdx.x, j = threadIdx.x;
  float av = transA ? A[j * 256 + i] : A[i * 256 + j];
  a[j] = s ? av * s[j] : av;
  __syncthreads();
  float acc = 0.f;
  if (transB) {
    for (int k = 0; k < 256; ++k) acc += a[k] * B[j * 256 + k];
  } else {
    for (int k = 0; k < 256; ++k) acc += a[k] * B[k * 256 + j];
  }
  if (accum) Cm[i * 256 + j] += acc;
  else Cm[i * 256 + j] = acc;
}

// ---------------- C (+)= u1 v1^T + u2 v2^T + u3 v3^T ----------------
__global__ void k_r1x3(float* __restrict__ C, const float* __restrict__ u1,
    const float* __restrict__ v1, const float* __restrict__ u2,
    const float* __restrict__ v2, const float* __restrict__ u3,
    const float* __restrict__ v3, int accum) {
  int i = blockIdx.x, j = threadIdx.x;
  float val = u1[i] * v1[j] + u2[i] * v2[j] + u3[i] * v3[j];
  if (accum) C[i * 256 + j] += val;
  else C[i * 256 + j] = val;
}

// ---------------- s-vectors for scalar rank-1 terms ----------------
__global__ void k_mixvec(const float* __restrict__ scal, const float* __restrict__ x2,
    const float* __restrict__ yv, const float* __restrict__ b3,
    float* s1, float* s2, float* s3, float fN) {
  int j = threadIdx.x;
  s1[j] = scal[0] * x2[j] + scal[1] * yv[j] + scal[2] * b3[j];
  s2[j] = scal[3] * x2[j] + scal[4] * yv[j] + scal[5] * b3[j];
  s3[j] = scal[6] * x2[j] + scal[7] * yv[j] + fN * b3[j];
}

extern "C" void kernel_launch(void* const* d_in, const int* in_sizes, int n_in,
                              void* d_out, int out_size, void* d_ws, size_t ws_size,
                              hipStream_t stream) {
  const float* feature = (const float*)d_in[0];
  const int* src1 = (const int*)d_in[1];
  const int* dst1 = (const int*)d_in[2];
  const int* src2 = (const int*)d_in[3];
  const int* dst2 = (const int*)d_in[4];
  const float* W1 = (const float*)d_in[5];
  const float* b1 = (const float*)d_in[6];
  const float* W2 = (const float*)d_in[7];
  const float* b2 = (const float*)d_in[8];
  const float* W3 = (const float*)d_in[9];
  const float* b3 = (const float*)d_in[10];
  const float* gamma = (const float*)d_in[11];
  const float* beta = (const float*)d_in[12];
  const int N = in_sizes[0] / FDIM;
  const int E = in_sizes[1];
  float* out = (float*)d_out;

  // ---- workspace layout ----
  float* X = (float*)d_ws;
  size_t NF = (size_t)N * FDIM;
  float* Y = X + NF;
  float* G2A = Y + NF;
  int* rowptr = (int*)(G2A + NF);
  int* cursor = rowptr + (N + 1);
  int* esrc = cursor + N;
  float* vtmp = (float*)(esrc + E);
  float* d1 = vtmp + N; float* e1 = d1 + N; float* d2 = e1 + N; float* e2 = d2 + N;
  float* C = e2 + N;                 // 65536
  float* m_raw = C + 65536;          // 256
  float* tq = m_raw + 256; float* mv = tq + 256;
  float* Dv = mv + 256; float* x1 = Dv + 256; float* x2 = x1 + 256; float* yv = x2 + 256;
  float* Q = yv + 256; float* R1 = Q + 65536; float* R2 = R1 + 65536;
  float* Z = R2 + 65536; float* K1 = Z + 65536; float* Lm = K1 + 65536;
  float* p1 = Lm + 65536; float* p2 = p1 + 256; float* p3 = p2 + 256;
  float* q1 = p3 + 256; float* q2 = q1 + 256; float* q3 = q2 + 256;
  float* scal = q3 + 256;            // 16
  float* s1 = scal + 16; float* s2 = s1 + 256; float* s3 = s2 + 256;
  float* partial = X;                // 128*65536 floats <= NF, X is dead at gram time

  const int eb = (E + 255) / 256;
  const int nb = (N + 255) / 256;
  const int aggb = (N + 3) / 4;

  auto build = [&](const int* s_, const int* d_) {
    hipMemsetAsync(cursor, 0, (size_t)N * sizeof(int), stream);
    k_hist<<<eb, 256, 0, stream>>>(d_, cursor, E);
    k_scan<<<1, 1024, 0, stream>>>(cursor, rowptr, cursor, N);
    k_scatter<<<eb, 256, 0, stream>>>(s_, d_, cursor, esrc, E);
  };
  auto agg = [&](const float* in, float* o) {
    k_agg<<<aggb, 256, 0, stream>>>(in, rowptr, esrc, o, N);
  };
  auto gram = [&](const float* A_, const float* B_, float* Cout) {
    k_gram<<<dim3(2, 2, GRAM_KS), 256, 0, stream>>>(A_, B_, partial, N);
    k_gram_reduce<<<256, 256, 0, stream>>>(partial, Cout);
  };

  auto do_branch = [&](const int* s_, const int* d_, float* G2dst,
                       float* dvec, float* evec, float* xvec, float* Rdst) {
    build(s_, d_);
    agg(feature, X); agg(X, Y);                 // Y = G0
    gram(Y, Y, C);                              // C = G0^T G0 (partial aliases X: X dead)
    hipMemsetAsync(m_raw, 0, 256 * sizeof(float), stream);
    k_matvec3<<<512, 256, 0, stream>>>(Y, nullptr, nullptr, nullptr, nullptr, m_raw, N);
    k_quad<<<256, 256, 0, stream>>>(C, W1, m_raw, tq, mv);
    k_bncoef<<<1, 256, 0, stream>>>(tq, mv, b1, gamma, beta, W2, W3, b2, Dv, xvec, yv, N);
    k_mm_small<<<256, 256, 0, stream>>>(Q, W1, W2, Dv, 1, 1, 0);    // Q = W1^T D W2^T
    k_mm_small<<<256, 256, 0, stream>>>(Rdst, Q, W3, nullptr, 0, 1, 0); // R = Q W3^T
    k_deg<<<nb, 256, 0, stream>>>(rowptr, vtmp, N);                 // A*1
    k_aggv<<<nb, 256, 0, stream>>>(vtmp, rowptr, esrc, dvec, N);    // d = A^2 1
    k_aggv<<<nb, 256, 0, stream>>>(dvec, rowptr, esrc, vtmp, N);
    k_aggv<<<nb, 256, 0, stream>>>(vtmp, rowptr, esrc, evec, N);    // e = A^4 1
    agg(Y, X); agg(X, Y);                       // Y = G1
    agg(Y, X); agg(X, G2dst);                   // G2
  };

  do_branch(src1, dst1, G2A, d1, e1, x1, R1);
  do_branch(src2, dst2, Y, d2, e2, x2, R2);     // branch-2 G2 lands in Y

  // ---- final assembly ----
  hipMemsetAsync(p1, 0, (6 * 256 + 16) * sizeof(float), stream);  // p1..q3 + scal
  gram(G2A, Y, Z);                                                // Z = G2_1^T G2_2
  k_matvec3<<<512, 256, 0, stream>>>(G2A, e2, d2, p1, p2, p3, N);
  k_matvec3<<<512, 256, 0, stream>>>(Y, e1, d1, q1, q2, q3, N);
  k_dots<<<nb, 256, 0, stream>>>(d1, e1, d2, e2, scal, N);

  k_mm_small<<<256, 256, 0, stream>>>(K1, Z, R2, nullptr, 0, 0, 0);   // K1 = Z R2
  k_r1x3<<<256, 256, 0, stream>>>(K1, p1, x2, p2, yv, p3, b3, 1);     // K1 += rank-1s
  k_r1x3<<<256, 256, 0, stream>>>(Lm, x1, q1, yv, q2, b3, q3, 0);     // L
  k_mm_small<<<256, 256, 0, stream>>>(out, R1, K1, nullptr, 1, 0, 0); // out = R1^T K1
  k_mm_small<<<256, 256, 0, stream>>>(out, Lm, R2, nullptr, 0, 0, 1); // out += L R2
  k_mixvec<<<1, 256, 0, stream>>>(scal, x2, yv, b3, s1, s2, s3, (float)N);
  k_r1x3<<<256, 256, 0, stream>>>(out, x1, s1, yv, s2, b3, s3, 1);    // out += scalar terms
}

// Round 3
// 2501.835 us; speedup vs baseline: 1.0585x; 1.0250x over previous
//
#include <hip/hip_runtime.h>

#define FDIM 256
#define FV4 64
#define GRAM_KS 64

// ---------------- CSR build ----------------
__global__ void k_hist(const int* __restrict__ dst, int* __restrict__ deg, int E) {
  int e = blockIdx.x * 256 + threadIdx.x;
  if (e < E) atomicAdd(&deg[dst[e]], 1);
}

// block sums of 1024-element chunks
__global__ __launch_bounds__(256) void k_blksum(const int* __restrict__ deg,
    int* __restrict__ blksum, int n) {
  int b = blockIdx.x, tid = threadIdx.x;
  int base = b * 1024 + tid * 4;
  int s = 0;
#pragma unroll
  for (int k = 0; k < 4; ++k) if (base + k < n) s += deg[base + k];
  for (int off = 32; off; off >>= 1) s += __shfl_down(s, off);
  __shared__ int ws4[4];
  if ((tid & 63) == 0) ws4[tid >> 6] = s;
  __syncthreads();
  if (tid == 0) blksum[b] = ws4[0] + ws4[1] + ws4[2] + ws4[3];
}

// exclusive scan of block sums (one wave, chunked with carry)
__global__ void k_blkscan(const int* __restrict__ blksum, int* __restrict__ blkoff, int nblk) {
  int lane = threadIdx.x;
  int carry = 0;
  for (int base = 0; base < nblk; base += 64) {
    int v = (base + lane < nblk) ? blksum[base + lane] : 0;
    int x = v;
    for (int off = 1; off < 64; off <<= 1) { int y = __shfl_up(x, off); if (lane >= off) x += y; }
    if (base + lane < nblk) blkoff[base + lane] = carry + x - v;
    carry += __shfl(x, 63);
  }
}

// per-block exclusive scan + add block offset; writes rowptr and cursor (in-place over deg ok)
__global__ __launch_bounds__(256) void k_scan_blk(const int* __restrict__ deg,
    const int* __restrict__ blkoff, int* __restrict__ rowptr, int* __restrict__ cursor, int n) {
  int b = blockIdx.x, tid = threadIdx.x;
  int base = b * 1024 + tid * 4;
  int v[4];
#pragma unroll
  for (int k = 0; k < 4; ++k) v[k] = (base + k < n) ? deg[base + k] : 0;
  int s = v[0] + v[1] + v[2] + v[3];
  int lane = tid & 63, w = tid >> 6;
  int x = s;
  for (int off = 1; off < 64; off <<= 1) { int y = __shfl_up(x, off); if (lane >= off) x += y; }
  __shared__ int wsum[4];
  if (lane == 63) wsum[w] = x;
  __syncthreads();
  int wadd = 0;
  for (int i = 0; i < w; ++i) wadd += wsum[i];
  int run = blkoff[b] + wadd + x - s;   // exclusive prefix at position `base`
#pragma unroll
  for (int k = 0; k < 4; ++k) {
    if (base + k < n) { rowptr[base + k] = run; cursor[base + k] = run; }
    run += v[k];
  }
  if (n >= base && n <= base + 4) rowptr[n] = run;  // total (may double-write same value)
}

__global__ void k_scatter(const int* __restrict__ src, const int* __restrict__ dst,
    int* __restrict__ cursor, int* __restrict__ esrc, int E) {
  int e = blockIdx.x * 256 + threadIdx.x;
  if (e < E) {
    int p = atomicAdd(&cursor[dst[e]], 1);
    esrc[p] = src[e];
  }
}

// ---------------- feature aggregation (one wave per node, 4-wide MLP) ----------------
__global__ __launch_bounds__(256) void k_agg(const float* __restrict__ h,
    const int* __restrict__ rowptr, const int* __restrict__ esrc,
    float* __restrict__ out, int n) {
  int wid = ((blockIdx.x * 256) + threadIdx.x) >> 6;
  int lane = threadIdx.x & 63;
  if (wid >= n) return;
  int beg = rowptr[wid], end = rowptr[wid + 1];
  const float4* hv = (const float4*)h;
  float4 a0 = {0,0,0,0}, a1 = {0,0,0,0}, a2 = {0,0,0,0}, a3 = {0,0,0,0};
  int e = beg;
  for (; e + 4 <= end; e += 4) {
    int s0 = esrc[e], s1 = esrc[e+1], s2 = esrc[e+2], s3 = esrc[e+3];
    float4 v0 = hv[(size_t)s0 * FV4 + lane];
    float4 v1 = hv[(size_t)s1 * FV4 + lane];
    float4 v2 = hv[(size_t)s2 * FV4 + lane];
    float4 v3 = hv[(size_t)s3 * FV4 + lane];
    a0.x += v0.x; a0.y += v0.y; a0.z += v0.z; a0.w += v0.w;
    a1.x += v1.x; a1.y += v1.y; a1.z += v1.z; a1.w += v1.w;
    a2.x += v2.x; a2.y += v2.y; a2.z += v2.z; a2.w += v2.w;
    a3.x += v3.x; a3.y += v3.y; a3.z += v3.z; a3.w += v3.w;
  }
  if (e < end) {
    int i1 = min(e + 1, end - 1), i2 = min(e + 2, end - 1), i3 = min(e + 3, end - 1);
    float m1 = (e + 1 < end) ? 1.f : 0.f;
    float m2 = (e + 2 < end) ? 1.f : 0.f;
    float m3 = (e + 3 < end) ? 1.f : 0.f;
    float4 v0 = hv[(size_t)esrc[e]  * FV4 + lane];
    float4 v1 = hv[(size_t)esrc[i1] * FV4 + lane];
    float4 v2 = hv[(size_t)esrc[i2] * FV4 + lane];
    float4 v3 = hv[(size_t)esrc[i3] * FV4 + lane];
    a0.x += v0.x; a0.y += v0.y; a0.z += v0.z; a0.w += v0.w;
    a1.x += v1.x * m1; a1.y += v1.y * m1; a1.z += v1.z * m1; a1.w += v1.w * m1;
    a2.x += v2.x * m2; a2.y += v2.y * m2; a2.z += v2.z * m2; a2.w += v2.w * m2;
    a3.x += v3.x * m3; a3.y += v3.y * m3; a3.z += v3.z * m3; a3.w += v3.w * m3;
  }
  float4 r;
  r.x = (a0.x + a1.x) + (a2.x + a3.x);
  r.y = (a0.y + a1.y) + (a2.y + a3.y);
  r.z = (a0.z + a1.z) + (a2.z + a3.z);
  r.w = (a0.w + a1.w) + (a2.w + a3.w);
  ((float4*)out)[(size_t)wid * FV4 + lane] = r;
}

// ---------------- scalar aggregation (one wave per node, lane-parallel edges) ----------------
__global__ void k_deg(const int* __restrict__ rowptr, float* __restrict__ out, int n) {
  int v = blockIdx.x * 256 + threadIdx.x;
  if (v < n) out[v] = (float)(rowptr[v + 1] - rowptr[v]);
}

__global__ __launch_bounds__(256) void k_aggv(const float* __restrict__ in,
    const int* __restrict__ rowptr, const int* __restrict__ esrc,
    float* __restrict__ out, int n) {
  int wid = ((blockIdx.x * 256) + threadIdx.x) >> 6;
  int lane = threadIdx.x & 63;
  if (wid >= n) return;
  int beg = rowptr[wid], end = rowptr[wid + 1];
  float s = 0.f;
  for (int e = beg + lane; e < end; e += 64) s += in[esrc[e]];
  for (int off = 32; off; off >>= 1) s += __shfl_down(s, off);
  if (lane == 0) out[wid] = s;
}

// ---------------- Gram: partial[z] = X_chunk^T Y_chunk (128x128 tile/block) ----------------
__global__ __launch_bounds__(256) void k_gram(const float* __restrict__ Xm,
    const float* __restrict__ Ym, float* __restrict__ partial, int n) {
  __shared__ float Xs[16][128];
  __shared__ float Ys[16][128];
  int tid = threadIdx.x;
  int i0 = blockIdx.x * 128, j0 = blockIdx.y * 128;
  int z = blockIdx.z;
  int chunk = (n + GRAM_KS - 1) / GRAM_KS;
  int rb = z * chunk, re = min(n, rb + chunk);
  int lk = tid >> 4;
  int lc = (tid & 15) * 8;
  int ti = tid >> 4, tj = tid & 15;
  float acc[8][8] = {};
  for (int rr = rb; rr < re; rr += 16) {
    int r = rr + lk;
    float4 a0 = {0,0,0,0}, a1 = {0,0,0,0}, b0 = {0,0,0,0}, b1 = {0,0,0,0};
    if (r < re) {
      const float* xp = Xm + (size_t)r * 256 + i0 + lc;
      const float* yp = Ym + (size_t)r * 256 + j0 + lc;
      a0 = *(const float4*)xp; a1 = *(const float4*)(xp + 4);
      b0 = *(const float4*)yp; b1 = *(const float4*)(yp + 4);
    }
    *(float4*)&Xs[lk][lc] = a0; *(float4*)&Xs[lk][lc + 4] = a1;
    *(float4*)&Ys[lk][lc] = b0; *(float4*)&Ys[lk][lc + 4] = b1;
    __syncthreads();
#pragma unroll
    for (int k = 0; k < 16; ++k) {
      float av[8], bv[8];
      *(float4*)&av[0] = *(const float4*)&Xs[k][ti * 8];
      *(float4*)&av[4] = *(const float4*)&Xs[k][ti * 8 + 4];
      *(float4*)&bv[0] = *(const float4*)&Ys[k][tj * 8];
      *(float4*)&bv[4] = *(const float4*)&Ys[k][tj * 8 + 4];
#pragma unroll
      for (int i = 0; i < 8; ++i)
#pragma unroll
        for (int j = 0; j < 8; ++j) acc[i][j] += av[i] * bv[j];
    }
    __syncthreads();
  }
  float* pout = partial + (size_t)z * 65536;
#pragma unroll
  for (int i = 0; i < 8; ++i) {
    int row = i0 + ti * 8 + i;
#pragma unroll
    for (int j = 0; j < 8; j += 4)
      *(float4*)(pout + (size_t)row * 256 + j0 + tj * 8 + j) = *(float4*)&acc[i][j];
  }
}

__global__ void k_gram_reduce(const float* __restrict__ partial, float* __restrict__ C) {
  int idx = blockIdx.x * 256 + threadIdx.x;
  float s = 0.f;
  for (int z = 0; z < GRAM_KS; ++z) s += partial[(size_t)z * 65536 + idx];
  C[idx] = s;
}

// ---------------- weighted column sums ----------------
__global__ __launch_bounds__(256) void k_matvec3(const float* __restrict__ G,
    const float* __restrict__ wA, const float* __restrict__ wB,
    float* outA, float* outB, float* outS, int n) {
  int f = threadIdx.x;
  float sA = 0.f, sB = 0.f, sS = 0.f;
  for (int r = blockIdx.x; r < n; r += gridDim.x) {
    float v = G[(size_t)r * 256 + f];
    if (wA) sA += v * wA[r];
    if (wB) sB += v * wB[r];
    sS += v;
  }
  if (outA) atomicAdd(&outA[f], sA);
  if (outB) atomicAdd(&outB[f], sB);
  atomicAdd(&outS[f], sS);
}

// ---------------- 8 scalar reductions over d/e vectors ----------------
__global__ __launch_bounds__(256) void k_dots(const float* __restrict__ d1,
    const float* __restrict__ e1, const float* __restrict__ d2,
    const float* __restrict__ e2, float* scal, int n) {
  int i = blockIdx.x * 256 + threadIdx.x;
  float a = 0, b = 0, c = 0, d = 0;
  if (i < n) { a = d1[i]; b = e1[i]; c = d2[i]; d = e2[i]; }
  float v[8] = { b * d, b * c, b, a * d, a * c, a, d, c };
#pragma unroll
  for (int j = 0; j < 8; ++j) {
    float x = v[j];
    for (int off = 32; off; off >>= 1) x += __shfl_down(x, off);
    v[j] = x;
  }
  if ((threadIdx.x & 63) == 0)
#pragma unroll
    for (int j = 0; j < 8; ++j) atomicAdd(&scal[j], v[j]);
}

// ---------------- t_j = w_j^T C w_j ; mv_j = w_j . m_raw ----------------
__global__ __launch_bounds__(256) void k_quad(const float* __restrict__ C,
    const float* __restrict__ W1, const float* __restrict__ m_raw,
    float* __restrict__ t, float* __restrict__ mv) {
  __shared__ float w[256];
  __shared__ float r1[256], r2[256];
  int j = blockIdx.x, tid = threadIdx.x;
  w[tid] = W1[j * 256 + tid];
  __syncthreads();
  float v = 0.f;
  for (int k = 0; k < 256; ++k) v += w[k] * C[k * 256 + tid];
  r1[tid] = v * w[tid];
  r2[tid] = w[tid] * m_raw[tid];
  __syncthreads();
  for (int off = 128; off; off >>= 1) {
    if (tid < off) { r1[tid] += r1[tid + off]; r2[tid] += r2[tid + off]; }
    __syncthreads();
  }
  if (tid == 0) { t[j] = r1[0]; mv[j] = r2[0]; }
}

// ---------------- BN coefficients + x = W3 W2 c, y = W3 b2 ----------------
__global__ __launch_bounds__(256) void k_bncoef(const float* __restrict__ t,
    const float* __restrict__ mv, const float* __restrict__ b1,
    const float* __restrict__ gamma, const float* __restrict__ beta,
    const float* __restrict__ W2, const float* __restrict__ W3,
    const float* __restrict__ b2, float* Dv, float* xv, float* yv, int n) {
  __shared__ float c[256], u[256];
  int j = threadIdx.x;
  float invn = 1.f / (float)n;
  float mean = mv[j] * invn + b1[j];
  float E2 = t[j] * invn + 2.f * b1[j] * mv[j] * invn + b1[j] * b1[j];
  float var = E2 - mean * mean;
  float D = gamma[j] * rsqrtf(var + 1e-5f);
  Dv[j] = D;
  c[j] = D * (b1[j] - mean) + beta[j];
  __syncthreads();
  float uu = 0.f;
  for (int k = 0; k < 256; ++k) uu += W2[j * 256 + k] * c[k];
  u[j] = uu;
  __syncthreads();
  float xx = 0.f, yy = 0.f;
  for (int k = 0; k < 256; ++k) {
    xx += W3[j * 256 + k] * u[k];
    yy += W3[j * 256 + k] * b2[k];
  }
  xv[j] = xx;
  yv[j] = yy;
}

// ---------------- small 256x256 matmul ----------------
__global__ __launch_bounds__(256) void k_mm_small(float* __restrict__ Cm,
    const float* __restrict__ A, const float* __restrict__ B,
    const float* __restrict__ s, int transA, int transB, int accum) {
  __shared__ float a[256];
  int i = blockIdx.x, j = threadIdx.x;
  float av = transA ? A[j * 256 + i] : A[i * 256 + j];
  a[j] = s ? av * s[j] : av;
  __syncthreads();
  float acc = 0.f;
  if (transB) {
    for (int k = 0; k < 256; ++k) acc += a[k] * B[j * 256 + k];
  } else {
    for (int k = 0; k < 256; ++k) acc += a[k] * B[k * 256 + j];
  }
  if (accum) Cm[i * 256 + j] += acc;
  else Cm[i * 256 + j] = acc;
}

// ---------------- C (+)= u1 v1^T + u2 v2^T + u3 v3^T ----------------
__global__ void k_r1x3(float* __restrict__ C, const float* __restrict__ u1,
    const float* __restrict__ v1, const float* __restrict__ u2,
    const float* __restrict__ v2, const float* __restrict__ u3,
    const float* __restrict__ v3, int accum) {
  int i = blockIdx.x, j = threadIdx.x;
  float val = u1[i] * v1[j] + u2[i] * v2[j] + u3[i] * v3[j];
  if (accum) C[i * 256 + j] += val;
  else C[i * 256 + j] = val;
}

__global__ void k_mixvec(const float* __restrict__ scal, const float* __restrict__ x2,
    const float* __restrict__ yv, const float* __restrict__ b3,
    float* s1, float* s2, float* s3, float fN) {
  int j = threadIdx.x;
  s1[j] = scal[0] * x2[j] + scal[1] * yv[j] + scal[2] * b3[j];
  s2[j] = scal[3] * x2[j] + scal[4] * yv[j] + scal[5] * b3[j];
  s3[j] = scal[6] * x2[j] + scal[7] * yv[j] + fN * b3[j];
}

extern "C" void kernel_launch(void* const* d_in, const int* in_sizes, int n_in,
                              void* d_out, int out_size, void* d_ws, size_t ws_size,
                              hipStream_t stream) {
  const float* feature = (const float*)d_in[0];
  const int* src1 = (const int*)d_in[1];
  const int* dst1 = (const int*)d_in[2];
  const int* src2 = (const int*)d_in[3];
  const int* dst2 = (const int*)d_in[4];
  const float* W1 = (const float*)d_in[5];
  const float* b1 = (const float*)d_in[6];
  const float* W2 = (const float*)d_in[7];
  const float* b2 = (const float*)d_in[8];
  const float* W3 = (const float*)d_in[9];
  const float* b3 = (const float*)d_in[10];
  const float* gamma = (const float*)d_in[11];
  const float* beta = (const float*)d_in[12];
  const int N = in_sizes[0] / FDIM;
  const int E = in_sizes[1];
  float* out = (float*)d_out;

  // ---- workspace layout ----
  float* X = (float*)d_ws;
  size_t NF = (size_t)N * FDIM;
  float* Y = X + NF;
  float* G2A = Y + NF;
  int* rowptr = (int*)(G2A + NF);
  int* cursor = rowptr + (N + 1);
  int* esrc = cursor + N;
  float* vtmp = (float*)(esrc + E);
  float* d1 = vtmp + N; float* e1 = d1 + N; float* d2 = e1 + N; float* e2 = d2 + N;
  float* C = e2 + N;
  float* m_raw = C + 65536;
  float* tq = m_raw + 256; float* mv = tq + 256;
  float* Dv = mv + 256; float* x1 = Dv + 256; float* x2 = x1 + 256; float* yv = x2 + 256;
  float* Q = yv + 256; float* R1 = Q + 65536; float* R2 = R1 + 65536;
  float* Z = R2 + 65536; float* K1 = Z + 65536; float* Lm = K1 + 65536;
  float* p1 = Lm + 65536; float* p2 = p1 + 256; float* p3 = p2 + 256;
  float* q1 = p3 + 256; float* q2 = q1 + 256; float* q3 = q2 + 256;
  float* scal = q3 + 256;
  float* s1 = scal + 16; float* s2 = s1 + 256; float* s3 = s2 + 256;
  int* blksum = (int*)(s3 + 256);
  int* blkoff = blksum + 1024;
  float* partial = X;   // GRAM_KS*65536 floats <= NF; X dead at gram time

  const int eb = (E + 255) / 256;
  const int nb = (N + 255) / 256;
  const int aggb = (N + 3) / 4;
  const int nblk = (N + 1023) / 1024;

  auto build = [&](const int* s_, const int* d_) {
    hipMemsetAsync(cursor, 0, (size_t)N * sizeof(int), stream);
    k_hist<<<eb, 256, 0, stream>>>(d_, cursor, E);
    k_blksum<<<nblk, 256, 0, stream>>>(cursor, blksum, N);
    k_blkscan<<<1, 64, 0, stream>>>(blksum, blkoff, nblk);
    k_scan_blk<<<nblk, 256, 0, stream>>>(cursor, blkoff, rowptr, cursor, N);
    k_scatter<<<eb, 256, 0, stream>>>(s_, d_, cursor, esrc, E);
  };
  auto agg = [&](const float* in, float* o) {
    k_agg<<<aggb, 256, 0, stream>>>(in, rowptr, esrc, o, N);
  };
  auto gram = [&](const float* A_, const float* B_, float* Cout) {
    k_gram<<<dim3(2, 2, GRAM_KS), 256, 0, stream>>>(A_, B_, partial, N);
    k_gram_reduce<<<256, 256, 0, stream>>>(partial, Cout);
  };

  auto do_branch = [&](const int* s_, const int* d_, float* G2dst,
                       float* dvec, float* evec, float* xvec, float* Rdst) {
    build(s_, d_);
    agg(feature, X); agg(X, Y);                 // Y = G0
    gram(Y, Y, C);                              // C = G0^T G0
    hipMemsetAsync(m_raw, 0, 256 * sizeof(float), stream);
    k_matvec3<<<512, 256, 0, stream>>>(Y, nullptr, nullptr, nullptr, nullptr, m_raw, N);
    k_quad<<<256, 256, 0, stream>>>(C, W1, m_raw, tq, mv);
    k_bncoef<<<1, 256, 0, stream>>>(tq, mv, b1, gamma, beta, W2, W3, b2, Dv, xvec, yv, N);
    k_mm_small<<<256, 256, 0, stream>>>(Q, W1, W2, Dv, 1, 1, 0);
    k_mm_small<<<256, 256, 0, stream>>>(Rdst, Q, W3, nullptr, 0, 1, 0);
    k_deg<<<nb, 256, 0, stream>>>(rowptr, vtmp, N);
    k_aggv<<<aggb, 256, 0, stream>>>(vtmp, rowptr, esrc, dvec, N);   // d = A^2 1
    k_aggv<<<aggb, 256, 0, stream>>>(dvec, rowptr, esrc, vtmp, N);
    k_aggv<<<aggb, 256, 0, stream>>>(vtmp, rowptr, esrc, evec, N);   // e = A^4 1
    agg(Y, X); agg(X, Y);                       // Y = G1
    agg(Y, X); agg(X, G2dst);                   // G2
  };

  do_branch(src1, dst1, G2A, d1, e1, x1, R1);
  do_branch(src2, dst2, Y, d2, e2, x2, R2);

  // ---- final assembly ----
  hipMemsetAsync(p1, 0, (6 * 256 + 16) * sizeof(float), stream);
  gram(G2A, Y, Z);                                                // Z = G2_1^T G2_2
  k_matvec3<<<512, 256, 0, stream>>>(G2A, e2, d2, p1, p2, p3, N);
  k_matvec3<<<512, 256, 0, stream>>>(Y, e1, d1, q1, q2, q3, N);
  k_dots<<<nb, 256, 0, stream>>>(d1, e1, d2, e2, scal, N);

  k_mm_small<<<256, 256, 0, stream>>>(K1, Z, R2, nullptr, 0, 0, 0);
  k_r1x3<<<256, 256, 0, stream>>>(K1, p1, x2, p2, yv, p3, b3, 1);
  k_r1x3<<<256, 256, 0, stream>>>(Lm, x1, q1, yv, q2, b3, q3, 0);
  k_mm_small<<<256, 256, 0, stream>>>(out, R1, K1, nullptr, 1, 0, 0);
  k_mm_small<<<256, 256, 0, stream>>>(out, Lm, R2, nullptr, 0, 0, 1);
  k_mixvec<<<1, 256, 0, stream>>>(scal, x2, yv, b3, s1, s2, s3, (float)N);
  k_r1x3<<<256, 256, 0, stream>>>(out, x1, s1, yv, s2, b3, s3, 1);
}